// Round 1
// baseline (233.143 us; speedup 1.0000x reference)
//
#include <hip/hip_runtime.h>
#include <hip/hip_bf16.h>

// Problem constants (fixed by setup_inputs)
#define BATCH    4
#define NPOINT   2048
#define NSUP     16384
#define NCHAN    64
#define NSAMPLE  32
#define R2       0.01f   // f32(0.1*0.1) == f32(0.01)

// ---------------------------------------------------------------------------
// Kernel 1: ball query — one 64-lane wave per query point.
// Reference semantics: scan support points in index order, take first 32 with
// d2 < r^2; pad remaining slots with the first found index (0 if none).
// d2 computed with explicit _rn ops in the reference order ((dx^2+dy^2)+dz^2)
// to avoid FMA contraction flipping borderline comparisons.
// ---------------------------------------------------------------------------
__global__ __launch_bounds__(256) void ball_query_kernel(
    const float* __restrict__ query,    // (B, NPOINT, 3)
    const float* __restrict__ support,  // (B, NSUP, 3)
    int* __restrict__ idx_out)          // (B*NPOINT, NSAMPLE)
{
    const int wid  = (blockIdx.x * blockDim.x + threadIdx.x) >> 6;  // global wave id
    const int lane = threadIdx.x & 63;
    if (wid >= BATCH * NPOINT) return;

    const int b = wid >> 11;       // / NPOINT
    const int q = wid & (NPOINT - 1);

    const float* qc = query + ((size_t)(b * NPOINT + q)) * 3;
    const float qx = qc[0], qy = qc[1], qz = qc[2];

    const float* sup = support + (size_t)b * NSUP * 3;
    int* out = idx_out + ((size_t)wid << 5);

    int cnt = 0;
    int first = 0;

    for (int base = 0; base < NSUP && cnt < NSAMPLE; base += 64) {
        const int j = base + lane;
        const float* p = sup + (size_t)j * 3;
        const float dx = __fsub_rn(qx, p[0]);
        const float dy = __fsub_rn(qy, p[1]);
        const float dz = __fsub_rn(qz, p[2]);
        const float d2 = __fadd_rn(__fadd_rn(__fmul_rn(dx, dx), __fmul_rn(dy, dy)),
                                   __fmul_rn(dz, dz));
        const bool in = d2 < R2;
        const unsigned long long m = __ballot(in);
        if (m) {
            if (cnt == 0) first = base + __builtin_ctzll(m);
            const unsigned long long ltmask = (lane == 0) ? 0ull : (~0ull >> (64 - lane));
            const int slot = cnt + __popcll(m & ltmask);
            if (in && slot < NSAMPLE) out[slot] = j;
            cnt += __popcll(m);
        }
    }
    if (cnt > NSAMPLE) cnt = NSAMPLE;
    // pad slots [cnt, NSAMPLE) with first-found index (0 if none found)
    if (lane >= cnt && lane < NSAMPLE) out[lane] = (cnt > 0) ? first : 0;
}

// ---------------------------------------------------------------------------
// Kernel 2: group — one 256-thread block per (b, q).
//   out0[b,c,q,s] = support[b, idx[b,q,s], c] - query[b,q,c]   (c in 0..2)
//   out1[b,c,q,s] = features[b, c, idx[b,q,s]]                 (c in 0..63)
// Writes are contiguous 128B per 32-thread group; feature reads are random
// 4B gathers within L2-resident 64KB channel rows.
// ---------------------------------------------------------------------------
__global__ __launch_bounds__(256) void group_kernel(
    const float* __restrict__ query,     // (B, NPOINT, 3)
    const float* __restrict__ support,   // (B, NSUP, 3)
    const float* __restrict__ features,  // (B, NCHAN, NSUP)
    const int* __restrict__ idx,         // (B*NPOINT, NSAMPLE)
    float* __restrict__ out0,            // (B, 3, NPOINT, NSAMPLE)
    float* __restrict__ out1)            // (B, NCHAN, NPOINT, NSAMPLE)
{
    const int bid = blockIdx.x;          // [0, B*NPOINT)
    const int b = bid >> 11;
    const int q = bid & (NPOINT - 1);
    const int t = threadIdx.x;

    __shared__ int sidx[NSAMPLE];
    if (t < NSAMPLE) sidx[t] = idx[((size_t)bid << 5) + t];
    __syncthreads();

    const int s = t & 31;

    // grouped_xyz (relative): 96 threads cover c=0..2, s=0..31
    if (t < 3 * NSAMPLE) {
        const int c = t >> 5;
        const int id = sidx[s];
        const float v = __fsub_rn(support[((size_t)(b * NSUP + id)) * 3 + c],
                                  query[((size_t)(b * NPOINT + q)) * 3 + c]);
        out0[(((size_t)(b * 3 + c) * NPOINT) + q) * NSAMPLE + s] = v;
    }

    // grouped_features: 8 passes x (8 channels x 32 samples)
    const float* fb = features + ((size_t)b * NCHAN) * NSUP;
    const int id = sidx[s];
#pragma unroll
    for (int c0 = 0; c0 < NCHAN; c0 += 8) {
        const int cc = c0 + (t >> 5);
        out1[(((size_t)(b * NCHAN + cc) * NPOINT) + q) * NSAMPLE + s] =
            fb[((size_t)cc << 14) + id];
    }
}

extern "C" void kernel_launch(void* const* d_in, const int* in_sizes, int n_in,
                              void* d_out, int out_size, void* d_ws, size_t ws_size,
                              hipStream_t stream) {
    const float* query    = (const float*)d_in[0];  // (4,2048,3)
    const float* support  = (const float*)d_in[1];  // (4,16384,3)
    const float* features = (const float*)d_in[2];  // (4,64,16384)

    float* out0 = (float*)d_out;                         // (4,3,2048,32)
    float* out1 = out0 + (size_t)BATCH * 3 * NPOINT * NSAMPLE;  // (4,64,2048,32)
    int* ws_idx = (int*)d_ws;                            // (4*2048, 32) = 1 MB

    // Kernel 1: 8192 waves, 4 waves (256 threads) per block -> 2048 blocks
    ball_query_kernel<<<(BATCH * NPOINT) / 4, 256, 0, stream>>>(query, support, ws_idx);
    // Kernel 2: one block per (b, q)
    group_kernel<<<BATCH * NPOINT, 256, 0, stream>>>(query, support, features, ws_idx,
                                                     out0, out1);
}

// Round 2
// 150.841 us; speedup vs baseline: 1.5456x; 1.5456x over previous
//
#include <hip/hip_runtime.h>
#include <hip/hip_bf16.h>

// Problem constants (fixed by setup_inputs)
#define BATCH    4
#define NPOINT   2048
#define NSUP     16384
#define NCHAN    64
#define NSAMPLE  32
#define R2       0.01f   // f32(0.1*0.1) == f32(0.01)

// ---------------------------------------------------------------------------
// Kernel 1: ball query — one 64-lane wave per query point, 4x ILP unroll.
// Four independent 64-point chunk loads are issued back-to-back (hides L2
// latency), then four ballot/slot phases. slot<NSAMPLE guard makes chunks
// past cnt>=32 harmless, so early-exit granularity is 256 points.
// d2 uses explicit _rn ops in reference order ((dx^2+dy^2)+dz^2) to avoid
// FMA contraction flipping borderline comparisons.
// ---------------------------------------------------------------------------
struct f3 { float x, y, z; };

__global__ __launch_bounds__(256) void ball_query_kernel(
    const float* __restrict__ query,    // (B, NPOINT, 3)
    const float* __restrict__ support,  // (B, NSUP, 3)
    int* __restrict__ idx_out)          // (B*NPOINT, NSAMPLE)
{
    const int wid  = (blockIdx.x * blockDim.x + threadIdx.x) >> 6;
    const int lane = threadIdx.x & 63;
    if (wid >= BATCH * NPOINT) return;

    const int b = wid >> 11;
    const float* qc = query + (size_t)wid * 3;
    const float qx = qc[0], qy = qc[1], qz = qc[2];

    const float* sup = support + (size_t)b * NSUP * 3;
    int* out = idx_out + ((size_t)wid << 5);

    int cnt = 0;
    int first = 0;
    const unsigned long long ltmask = (lane == 0) ? 0ull : (~0ull >> (64 - lane));

    for (int base = 0; base < NSUP; base += 256) {
        f3 P[4];
#pragma unroll
        for (int u = 0; u < 4; ++u) {
            const int j = base + u * 64 + lane;
            P[u] = *reinterpret_cast<const f3*>(sup + (size_t)j * 3);
        }
        unsigned long long M[4];
#pragma unroll
        for (int u = 0; u < 4; ++u) {
            const float dx = __fsub_rn(qx, P[u].x);
            const float dy = __fsub_rn(qy, P[u].y);
            const float dz = __fsub_rn(qz, P[u].z);
            const float d2 = __fadd_rn(__fadd_rn(__fmul_rn(dx, dx), __fmul_rn(dy, dy)),
                                       __fmul_rn(dz, dz));
            M[u] = __ballot(d2 < R2);
        }
#pragma unroll
        for (int u = 0; u < 4; ++u) {
            const unsigned long long m = M[u];
            if (m) {
                if (cnt == 0) first = base + u * 64 + __builtin_ctzll(m);
                const bool in = (m >> lane) & 1ull;
                const int slot = cnt + __popcll(m & ltmask);
                if (in && slot < NSAMPLE) out[slot] = base + u * 64 + lane;
                cnt += __popcll(m);
            }
        }
        if (cnt >= NSAMPLE) break;
    }
    if (cnt > NSAMPLE) cnt = NSAMPLE;
    if (lane >= cnt && lane < NSAMPLE) out[lane] = (cnt > 0) ? first : 0;
}

// ---------------------------------------------------------------------------
// Kernel T: transpose features (B,64,16384) -> ft (B,16384,64)
// so the per-sample channel gather becomes a contiguous 256B row read.
// ---------------------------------------------------------------------------
__global__ __launch_bounds__(256) void transpose_kernel(
    const float* __restrict__ features,  // (B, NCHAN, NSUP)
    float* __restrict__ ft)              // (B, NSUP, NCHAN)
{
    __shared__ float lds[64 * 65];
    const int blk = blockIdx.x;                 // B * (NSUP/64)
    const int b  = blk >> 8;                    // / 256
    const int p0 = (blk & 255) << 6;
    const int t  = threadIdx.x;

    const int pl = t & 63;
#pragma unroll
    for (int r0 = 0; r0 < 64; r0 += 4) {
        const int c = r0 + (t >> 6);
        lds[pl * 65 + c] = features[((size_t)(b * NCHAN + c) << 14) + p0 + pl];
    }
    __syncthreads();
    const int cl = t & 63;
#pragma unroll
    for (int r0 = 0; r0 < 64; r0 += 4) {
        const int p = r0 + (t >> 6);
        ft[((size_t)(b * NSUP + p0 + p) << 6) + cl] = lds[p * 65 + cl];
    }
}

// ---------------------------------------------------------------------------
// Kernel 2 (fast): group via transposed features — coalesced row gathers,
// LDS re-tile [c][s] (stride 33 -> 2-way bank alias = free), coalesced writes.
// ---------------------------------------------------------------------------
__global__ __launch_bounds__(256) void group_fast_kernel(
    const float* __restrict__ query,     // (B, NPOINT, 3)
    const float* __restrict__ support,   // (B, NSUP, 3)
    const float* __restrict__ ft,        // (B, NSUP, NCHAN) transposed
    const int* __restrict__ idx,         // (B*NPOINT, NSAMPLE)
    float* __restrict__ out0,            // (B, 3, NPOINT, NSAMPLE)
    float* __restrict__ out1)            // (B, NCHAN, NPOINT, NSAMPLE)
{
    const int bid = blockIdx.x;
    const int b = bid >> 11;
    const int q = bid & (NPOINT - 1);
    const int t = threadIdx.x;

    __shared__ int   sidx[NSAMPLE];
    __shared__ float tile[NCHAN * 33];

    if (t < NSAMPLE) sidx[t] = idx[((size_t)bid << 5) + t];
    __syncthreads();

    // gather phase: 8 lanes per sample row, two float4 each (256B/row coalesced)
    {
        const int s  = t >> 3;          // 0..31
        const int cg = t & 7;           // 0..7
        const int id = sidx[s];
        const float4* src = reinterpret_cast<const float4*>(
            ft + (((size_t)(b * NSUP + id)) << 6) + (cg << 3));
        const float4 v0 = src[0];
        const float4 v1 = src[1];
        const int c0 = cg << 3;
        tile[(c0 + 0) * 33 + s] = v0.x;
        tile[(c0 + 1) * 33 + s] = v0.y;
        tile[(c0 + 2) * 33 + s] = v0.z;
        tile[(c0 + 3) * 33 + s] = v0.w;
        tile[(c0 + 4) * 33 + s] = v1.x;
        tile[(c0 + 5) * 33 + s] = v1.y;
        tile[(c0 + 6) * 33 + s] = v1.z;
        tile[(c0 + 7) * 33 + s] = v1.w;
    }

    // grouped_xyz while the tile settles
    const int s = t & 31;
    if (t < 3 * NSAMPLE) {
        const int c = t >> 5;
        const int id = sidx[s];
        const float v = __fsub_rn(support[((size_t)(b * NSUP + id)) * 3 + c],
                                  query[((size_t)(b * NPOINT + q)) * 3 + c]);
        out0[(((size_t)(b * 3 + c) * NPOINT) + q) * NSAMPLE + s] = v;
    }
    __syncthreads();

    // write phase: coalesced out1 stores
#pragma unroll
    for (int c0 = 0; c0 < NCHAN; c0 += 8) {
        const int cc = c0 + (t >> 5);
        out1[(((size_t)(b * NCHAN + cc) * NPOINT) + q) * NSAMPLE + s] =
            tile[cc * 33 + s];
    }
}

// ---------------------------------------------------------------------------
// Fallback group (round-0 version) if ws_size can't hold transposed features.
// ---------------------------------------------------------------------------
__global__ __launch_bounds__(256) void group_kernel(
    const float* __restrict__ query,
    const float* __restrict__ support,
    const float* __restrict__ features,
    const int* __restrict__ idx,
    float* __restrict__ out0,
    float* __restrict__ out1)
{
    const int bid = blockIdx.x;
    const int b = bid >> 11;
    const int q = bid & (NPOINT - 1);
    const int t = threadIdx.x;

    __shared__ int sidx[NSAMPLE];
    if (t < NSAMPLE) sidx[t] = idx[((size_t)bid << 5) + t];
    __syncthreads();

    const int s = t & 31;
    if (t < 3 * NSAMPLE) {
        const int c = t >> 5;
        const int id = sidx[s];
        const float v = __fsub_rn(support[((size_t)(b * NSUP + id)) * 3 + c],
                                  query[((size_t)(b * NPOINT + q)) * 3 + c]);
        out0[(((size_t)(b * 3 + c) * NPOINT) + q) * NSAMPLE + s] = v;
    }

    const float* fb = features + ((size_t)b * NCHAN) * NSUP;
    const int id = sidx[s];
#pragma unroll
    for (int c0 = 0; c0 < NCHAN; c0 += 8) {
        const int cc = c0 + (t >> 5);
        out1[(((size_t)(b * NCHAN + cc) * NPOINT) + q) * NSAMPLE + s] =
            fb[((size_t)cc << 14) + id];
    }
}

extern "C" void kernel_launch(void* const* d_in, const int* in_sizes, int n_in,
                              void* d_out, int out_size, void* d_ws, size_t ws_size,
                              hipStream_t stream) {
    const float* query    = (const float*)d_in[0];  // (4,2048,3)
    const float* support  = (const float*)d_in[1];  // (4,16384,3)
    const float* features = (const float*)d_in[2];  // (4,64,16384)

    float* out0 = (float*)d_out;
    float* out1 = out0 + (size_t)BATCH * 3 * NPOINT * NSAMPLE;

    const size_t idx_bytes = (size_t)BATCH * NPOINT * NSAMPLE * sizeof(int);   // 1 MB
    const size_t ft_bytes  = (size_t)BATCH * NSUP * NCHAN * sizeof(float);     // 16 MB
    int*   ws_idx = (int*)d_ws;
    float* ft     = (float*)((char*)d_ws + idx_bytes);
    const bool big_ws = ws_size >= idx_bytes + ft_bytes;

    ball_query_kernel<<<(BATCH * NPOINT) / 4, 256, 0, stream>>>(query, support, ws_idx);

    if (big_ws) {
        transpose_kernel<<<BATCH * (NSUP / 64), 256, 0, stream>>>(features, ft);
        group_fast_kernel<<<BATCH * NPOINT, 256, 0, stream>>>(query, support, ft, ws_idx,
                                                              out0, out1);
    } else {
        group_kernel<<<BATCH * NPOINT, 256, 0, stream>>>(query, support, features, ws_idx,
                                                         out0, out1);
    }
}

// Round 6
// 142.843 us; speedup vs baseline: 1.6322x; 1.0560x over previous
//
#include <hip/hip_runtime.h>
#include <hip/hip_bf16.h>

// Problem constants (fixed by setup_inputs)
#define BATCH    4
#define NPOINT   2048
#define NSUP     16384
#define NCHAN    64
#define NSAMPLE  32
#define R2       0.01f   // f32(0.1*0.1) == f32(0.01)

// ---------------------------------------------------------------------------
// Kernel 1: ball query — one 64-lane wave per query point, 4x ILP unroll,
// ONE WAVE PER BLOCK so early-exiting waves release their CU slot and the
// scheduler refills from the 8192-block pool (fixes the 49%-occupancy stall
// seen with 4-wave blocks).
// d2 uses explicit _rn ops in reference order ((dx^2+dy^2)+dz^2) to avoid
// FMA contraction flipping borderline comparisons.
// ---------------------------------------------------------------------------
struct f3 { float x, y, z; };

__global__ __launch_bounds__(64, 8) void ball_query_kernel(
    const float* __restrict__ query,    // (B, NPOINT, 3)
    const float* __restrict__ support,  // (B, NSUP, 3)
    int* __restrict__ idx_out)          // (B*NPOINT, NSAMPLE)
{
    const int wid  = blockIdx.x;        // one wave per block
    const int lane = threadIdx.x;

    const int b = wid >> 11;
    const float* qc = query + (size_t)wid * 3;
    const float qx = qc[0], qy = qc[1], qz = qc[2];

    const float* sup = support + (size_t)b * NSUP * 3;
    int* out = idx_out + ((size_t)wid << 5);

    int cnt = 0;
    int first = 0;
    const unsigned long long ltmask = (lane == 0) ? 0ull : (~0ull >> (64 - lane));

    for (int base = 0; base < NSUP; base += 256) {
        f3 P[4];
#pragma unroll
        for (int u = 0; u < 4; ++u) {
            const int j = base + u * 64 + lane;
            P[u] = *reinterpret_cast<const f3*>(sup + (size_t)j * 3);
        }
        unsigned long long M[4];
#pragma unroll
        for (int u = 0; u < 4; ++u) {
            const float dx = __fsub_rn(qx, P[u].x);
            const float dy = __fsub_rn(qy, P[u].y);
            const float dz = __fsub_rn(qz, P[u].z);
            const float d2 = __fadd_rn(__fadd_rn(__fmul_rn(dx, dx), __fmul_rn(dy, dy)),
                                       __fmul_rn(dz, dz));
            M[u] = __ballot(d2 < R2);
        }
#pragma unroll
        for (int u = 0; u < 4; ++u) {
            const unsigned long long m = M[u];
            if (m) {
                if (cnt == 0) first = base + u * 64 + __builtin_ctzll(m);
                const bool in = (m >> lane) & 1ull;
                const int slot = cnt + __popcll(m & ltmask);
                if (in && slot < NSAMPLE) out[slot] = base + u * 64 + lane;
                cnt += __popcll(m);
            }
        }
        if (cnt >= NSAMPLE) break;
    }
    if (cnt > NSAMPLE) cnt = NSAMPLE;
    if (lane >= cnt && lane < NSAMPLE) out[lane] = (cnt > 0) ? first : 0;
}

// ---------------------------------------------------------------------------
// Kernel 2: feature group — one 1024-thread block per (b, c) channel row.
// The whole 64KB channel row is staged in LDS; gathers become random
// ds_read_b32 (cheap) and out1 writes are fully coalesced float4 stores.
// No transpose pass, no L3-latency row gathers.
// ---------------------------------------------------------------------------
__global__ __launch_bounds__(1024) void group_feat_kernel(
    const float* __restrict__ features,  // (B, NCHAN, NSUP)
    const int*   __restrict__ idx,       // (B, NPOINT*NSAMPLE)
    float*       __restrict__ out1)      // (B, NCHAN, NPOINT*NSAMPLE)
{
    __shared__ float row[NSUP];          // 64 KB
    const int bc = blockIdx.x;           // 0..255  (b*NCHAN + c)
    const int b  = bc >> 6;
    const int t  = threadIdx.x;

    // stage: 16384 floats = 4096 float4, 1024 threads -> 4 each (coalesced)
    const float4* src4 = reinterpret_cast<const float4*>(features + ((size_t)bc << 14));
    float4* row4 = reinterpret_cast<float4*>(row);
#pragma unroll
    for (int i = 0; i < 4; ++i)
        row4[i * 1024 + t] = src4[i * 1024 + t];
    __syncthreads();

    // gather: 65536 outputs = 16384 int4/float4 groups, 1024 threads -> 16 each
    const int4* idx4 = reinterpret_cast<const int4*>(idx + ((size_t)b << 16));
    float4* dst4 = reinterpret_cast<float4*>(out1 + ((size_t)bc << 16));
#pragma unroll 4
    for (int i = t; i < (NPOINT * NSAMPLE / 4); i += 1024) {
        const int4 id = idx4[i];
        float4 v;
        v.x = row[id.x];
        v.y = row[id.y];
        v.z = row[id.z];
        v.w = row[id.w];
        dst4[i] = v;
    }
}

// ---------------------------------------------------------------------------
// Kernel 3: grouped_xyz — thread per (b,q,s); 3 coalesced c-plane stores.
// support (192KB/batch) and query are L2-resident.
// ---------------------------------------------------------------------------
__global__ __launch_bounds__(256) void group_xyz_kernel(
    const float* __restrict__ query,     // (B, NPOINT, 3)
    const float* __restrict__ support,   // (B, NSUP, 3)
    const int*   __restrict__ idx,       // (B, NPOINT, NSAMPLE)
    float*       __restrict__ out0)      // (B, 3, NPOINT, NSAMPLE)
{
    const int g = blockIdx.x * 256 + threadIdx.x;   // 0 .. B*NPOINT*NSAMPLE-1
    const int b  = g >> 16;
    const int qs = g & (NPOINT * NSAMPLE - 1);
    const int q  = qs >> 5;

    const int id = idx[g];
    const f3 sp = *reinterpret_cast<const f3*>(support + ((size_t)(b * NSUP + id)) * 3);
    const f3 qp = *reinterpret_cast<const f3*>(query + ((size_t)(b * NPOINT + q)) * 3);

    const size_t base = ((size_t)b * 3) * (NPOINT * NSAMPLE) + qs;
    out0[base]                         = __fsub_rn(sp.x, qp.x);
    out0[base + NPOINT * NSAMPLE]      = __fsub_rn(sp.y, qp.y);
    out0[base + 2 * NPOINT * NSAMPLE]  = __fsub_rn(sp.z, qp.z);
}

extern "C" void kernel_launch(void* const* d_in, const int* in_sizes, int n_in,
                              void* d_out, int out_size, void* d_ws, size_t ws_size,
                              hipStream_t stream) {
    const float* query    = (const float*)d_in[0];  // (4,2048,3)
    const float* support  = (const float*)d_in[1];  // (4,16384,3)
    const float* features = (const float*)d_in[2];  // (4,64,16384)

    float* out0 = (float*)d_out;                                 // (4,3,2048,32)
    float* out1 = out0 + (size_t)BATCH * 3 * NPOINT * NSAMPLE;   // (4,64,2048,32)
    int* ws_idx = (int*)d_ws;                                    // (4*2048, 32) = 1 MB

    // one wave per block: 8192 blocks of 64 threads
    ball_query_kernel<<<BATCH * NPOINT, 64, 0, stream>>>(query, support, ws_idx);

    // grouped_xyz: 262144 elements / 256
    group_xyz_kernel<<<(BATCH * NPOINT * NSAMPLE) / 256, 256, 0, stream>>>(
        query, support, ws_idx, out0);

    // grouped_features: one block per (b,c)
    group_feat_kernel<<<BATCH * NCHAN, 1024, 0, stream>>>(features, ws_idx, out1);
}